// Round 19
// baseline (156.060 us; speedup 1.0000x reference)
//
#include <hip/hip_runtime.h>
#include <math.h>

// ---------------- constants ----------------
#define BIGV      1e9f
#define WARP_PEN  134.4f
#define MASK_INF_C 100000.0f

#define B   8
#define H   192
#define T   400
#define NP  401                  // padded matrix dim (0..400)
#define NPROB 16                 // 2 dirs x 8 batches
#define TSLAB 166464             // diag-staged D floats per problem (2601 tiles x 64)
#define SBLOCKS 768              // scalar-loss blocks in fused kernel
#define KLBLOCKS (49 * NPROB)    // 784 kl_gemm blocks

typedef float f32x4 __attribute__((ext_vector_type(4)));

// ---------------- workspace layout (float offsets) ----------------
#define SLOT_OFF 16
#define LSP_OFF 160
#define LSQ_OFF (160 + B*T)
#define C1P_OFF (160 + 2*B*T)
#define C1Q_OFF (160 + 3*B*T)
#define DMAT_OFF (160 + 4*B*T)   // 12960 floats, 16B aligned

// Diagonal-staged tile layout (verified R16/R17).
__device__ __forceinline__ int diag_len(int s) { return (s <= 50) ? s + 1 : 101 - s; }
__device__ __forceinline__ int diag_i0 (int s) { return (s <= 50) ? 0 : s - 50; }
__device__ __forceinline__ int diag_Cs (int s) {
    return (s <= 51) ? s * (s + 1) / 2 : 2601 - (101 - s) * (102 - s) / 2;
}

// DPP wave_shr:1 — lane i gets src from lane i-1; lane 0 gets `fill`.
__device__ __forceinline__ float wave_shr1(float src, float fill) {
    int r = __builtin_amdgcn_update_dpp(__float_as_int(fill), __float_as_int(src),
                                        0x138 /*wave_shr:1*/, 0xf, 0xf, false);
    return __int_as_float(r);
}

// ---------------- kernel 2: per-(b,t) column sums (4-way h-split) ----------
__global__ __launch_bounds__(256)
void colsum(const float* __restrict__ logs_p, const float* __restrict__ m_p,
            const float* __restrict__ logs_q, const float* __restrict__ m_q,
            float* __restrict__ ws) {
    int b = blockIdx.x / 7;
    int lane = threadIdx.x & 63;
    int hq = threadIdx.x >> 6;                 // 0..3, 48 h each
    int t = (blockIdx.x % 7) * 64 + lane;
    __shared__ float part[4][4][64];
    float lp_s = 0.f, lq_s = 0.f, c1p = 0.f, c1q = 0.f;
    if (t < T) {
        int base = b*H*T + hq*48*T + t;
        const float* LP = logs_p + base;
        const float* MP = m_p   + base;
        const float* LQ = logs_q + base;
        const float* MQ = m_q   + base;
#pragma unroll 4
        for (int h = 0; h < 48; ++h) {
            float lp = LP[h*T], mp = MP[h*T];
            float lq = LQ[h*T], mq = MQ[h*T];
            lp_s += lp;
            lq_s += lq;
            c1p += __expf(-2.f*lp) * mp * mp;
            c1q += __expf(-2.f*lq) * mq * mq;
        }
    }
    part[hq][0][lane] = lp_s;
    part[hq][1][lane] = lq_s;
    part[hq][2][lane] = c1p;
    part[hq][3][lane] = c1q;
    __syncthreads();
    if (hq == 0 && t < T) {
        float a0 = part[0][0][lane] + part[1][0][lane] + part[2][0][lane] + part[3][0][lane];
        float a1 = part[0][1][lane] + part[1][1][lane] + part[2][1][lane] + part[3][1][lane];
        float a2 = part[0][2][lane] + part[1][2][lane] + part[2][2][lane] + part[3][2][lane];
        float a3 = part[0][3][lane] + part[1][3][lane] + part[2][3][lane] + part[3][3][lane];
        ws[LSP_OFF + b*T + t] = a0;
        ws[LSQ_OFF + b*T + t] = a1;
        ws[C1P_OFF + b*T + t] = a2;
        ws[C1Q_OFF + b*T + t] = a3;
    }
}

// ---------------- fused kernel: KL GEMM (blocks 0..783) + scalar losses ----
// KH=16: LDS 17.5KB -> 8 blocks/CU (was 4 at KH=32, the R18 occupancy
// limiter: VALUBusy 33% with both pipes unsaturated). 2x waves -> 2x hiding.
#define TILE 64
#define KH 16
__global__ __launch_bounds__(256)
void fused_kl_scalar(const float* __restrict__ z_p, const float* __restrict__ m_p,
                     const float* __restrict__ logs_p,
                     const float* __restrict__ z_q, const float* __restrict__ m_q,
                     const float* __restrict__ logs_q,
                     const int* __restrict__ p_mask, const int* __restrict__ z_mask,
                     float* __restrict__ ws,
                     const float* __restrict__ mel, const float* __restrict__ melh,
                     const float* __restrict__ sg,  const float* __restrict__ se,
                     const float* __restrict__ fr,  const float* __restrict__ ff) {
    __shared__ __align__(16) float As [KH][TILE+4];
    __shared__ __align__(16) float AMs[KH][TILE+4];
    __shared__ __align__(16) float Zs [KH][TILE+4];
    __shared__ __align__(16) float Z2s[KH][TILE+4];
    __shared__ float red[4][8];

    if (blockIdx.x < KLBLOCKS) {
        // ---------------- kl_gemm path ----------------
        int prob = blockIdx.x / 49;
        int bx   = blockIdx.x % 49;
        int dir = prob >> 3, b = prob & 7;
        int tp = bx / 7, tq = bx % 7;
        int p0 = tp * TILE, q0 = tq * TILE;

        const float* lp_arr = dir ? logs_q : logs_p;
        const float* m_arr  = dir ? m_q    : m_p;
        const float* z_arr  = dir ? z_q    : z_p;
        const float* Lp = ws + (dir ? LSQ_OFF : LSP_OFF) + b*T;
        const float* Lq = ws + (dir ? LSP_OFF : LSQ_OFF) + b*T;
        const float* C1 = ws + (dir ? C1Q_OFF : C1P_OFF) + b*T;
        const int* rmask = dir ? z_mask : p_mask;
        const int* cmask = dir ? p_mask : z_mask;

        int tid = threadIdx.x;
        int tx = tid & 15, ty = tid >> 4;

        float acc1[4][4] = {{0.f}}, acc2[4][4] = {{0.f}};

        const float* lpB = lp_arr + b*H*T;
        const float* mB  = m_arr  + b*H*T;
        const float* zB  = z_arr  + b*H*T;

        for (int h0 = 0; h0 < H; h0 += KH) {
            for (int e = tid; e < KH*TILE; e += 256) {
                int hh = e >> 6, tt = e & 63;
                int pg = p0 + tt; if (pg > T-1) pg = T-1;
                int qg = q0 + tt; if (qg > T-1) qg = T-1;
                float lp = lpB[(h0+hh)*T + pg];
                float mv = mB [(h0+hh)*T + pg];
                float a  = __expf(-2.f*lp);
                As [hh][tt] = a;
                AMs[hh][tt] = a * mv;
                float zv = zB[(h0+hh)*T + qg];
                Zs [hh][tt] = zv;
                Z2s[hh][tt] = zv * zv;
            }
            __syncthreads();
#pragma unroll 8
            for (int hh = 0; hh < KH; ++hh) {
                const float4 av  = *(const float4*)(&As [hh][ty*4]);
                const float4 amv = *(const float4*)(&AMs[hh][ty*4]);
                const float4 zv  = *(const float4*)(&Zs [hh][tx*4]);
                const float4 z2v = *(const float4*)(&Z2s[hh][tx*4]);
                const float pa[4]  = {av.x, av.y, av.z, av.w};
                const float pam[4] = {amv.x, amv.y, amv.z, amv.w};
                const float qz[4]  = {zv.x, zv.y, zv.z, zv.w};
                const float qz2[4] = {z2v.x, z2v.y, z2v.z, z2v.w};
#pragma unroll
                for (int ii = 0; ii < 4; ++ii)
#pragma unroll
                    for (int jj = 0; jj < 4; ++jj) {
                        acc1[ii][jj] = fmaf(pa[ii],  qz2[jj], acc1[ii][jj]);
                        acc2[ii][jj] = fmaf(pam[ii], qz[jj],  acc2[ii][jj]);
                    }
            }
            __syncthreads();
        }

        // epilogue: kl value + pad/mask, DIAG-STAGED write (verified R16)
        float* Dm = ws + DMAT_OFF + (size_t)prob * TSLAB;
#pragma unroll
        for (int ii = 0; ii < 4; ++ii) {
            int p = p0 + ty*4 + ii;
            if (p > NP-1) continue;
            int pc = p < T ? p : T-1;
            float lpv = Lp[pc];
            float c1v = C1[pc];
            bool pmv = (p < T) && (rmask[b*T + p] != 0);
#pragma unroll
            for (int jj = 0; jj < 4; ++jj) {
                int q = q0 + tx*4 + jj;
                if (q > NP-1) continue;
                int qc = q < T ? q : T-1;
                bool qmv = (q < T) && (cmask[b*T + q] != 0);
                float val = lpv - Lq[qc] - 0.5f*(float)H
                          + 0.5f*(acc1[ii][jj] - 2.f*acc2[ii][jj] + c1v);
                float outv = (pmv != qmv) ? MASK_INF_C : ((!pmv && !qmv) ? 0.f : val);
                int I8 = p >> 3, J8 = q >> 3, sdg = I8 + J8;
                int len = diag_len(sdg), i0 = diag_i0(sdg), Cs = diag_Cs(sdg);
                int k = (p & 7) * 2 + ((q & 7) >> 2);
                int off = Cs*64 + (k*len + (I8 - i0))*4 + (q & 3);
                Dm[off] = outv;
            }
        }
    } else {
        // ---------------- scalar losses path ----------------
        float s0 = 0.f, s1 = 0.f, s2 = 0.f, s3 = 0.f, s4 = 0.f, s5 = 0.f;
        int tid = (blockIdx.x - KLBLOCKS) * 256 + threadIdx.x;
        const int stride = SBLOCKS * 256;

        const float4* fr4 = (const float4*)fr;
        const float4* ff4 = (const float4*)ff;
        for (int i = tid; i < 3072000; i += stride) {
            float4 a = fr4[i], b = ff4[i];
            s2 += fabsf(a.x - b.x) + fabsf(a.y - b.y) + fabsf(a.z - b.z) + fabsf(a.w - b.w);
        }
        const float4* m4 = (const float4*)mel;
        const float4* mh4 = (const float4*)melh;
        for (int i = tid; i < 64000; i += stride) {
            float4 a = m4[i], b = mh4[i];
            s3 += fabsf(a.x - b.x) + fabsf(a.y - b.y) + fabsf(a.z - b.z) + fabsf(a.w - b.w);
        }
        const float4* g4 = (const float4*)sg;
        const float4* e4 = (const float4*)se;
        for (int i = tid; i < 4800; i += stride) {
            float4 a = g4[i], b = e4[i];
            float gx = 1.f - a.x, gy = 1.f - a.y, gz = 1.f - a.z, gw = 1.f - a.w;
            s0 += gx*gx + gy*gy + gz*gz + gw*gw;
            float hx = 1.f - b.x, hy = 1.f - b.y, hz = 1.f - b.z, hw = 1.f - b.w;
            s1 += hx*hx + hy*hy + hz*hz + hw*hw;
        }
        for (int i = tid; i < B*T; i += stride) {
            s4 += (float)p_mask[i];
            s5 += (float)z_mask[i];
        }
        for (int off = 32; off > 0; off >>= 1) {
            s0 += __shfl_down(s0, off); s1 += __shfl_down(s1, off);
            s2 += __shfl_down(s2, off); s3 += __shfl_down(s3, off);
            s4 += __shfl_down(s4, off); s5 += __shfl_down(s5, off);
        }
        int wid = threadIdx.x >> 6;
        if ((threadIdx.x & 63) == 0) {
            red[wid][0] = s0; red[wid][1] = s1; red[wid][2] = s2;
            red[wid][3] = s3; red[wid][4] = s4; red[wid][5] = s5;
        }
        __syncthreads();
        if (threadIdx.x == 0) {
            float t0 = 0.f, t1 = 0.f, t2 = 0.f, t3 = 0.f, t4 = 0.f, t5 = 0.f;
#pragma unroll
            for (int w = 0; w < 4; ++w) {
                t0 += red[w][0]; t1 += red[w][1]; t2 += red[w][2];
                t3 += red[w][3]; t4 += red[w][4]; t5 += red[w][5];
            }
            float* slot = ws + SLOT_OFF + (blockIdx.x & 7) * 16;
            atomicAdd(&slot[0], t0); atomicAdd(&slot[1], t1);
            atomicAdd(&slot[2], t2); atomicAdd(&slot[3], t3);
            atomicAdd(&slot[4], t4); atomicAdd(&slot[5], t5);
        }
    }
}

// ---------------- kernel 4: DTW tile wavefront — STANDALONE ----------------
// 16 blocks x 64 threads, launch_bounds(64,1). Load issue hoisted to the top
// of each step (max lead time before consumption next step).
__global__ __launch_bounds__(64, 1)
void dtw_diag(const float* __restrict__ Dd, float* __restrict__ acc) {
    int prob = blockIdx.x;
    int lane = threadIdx.x;
    const float* Dp = Dd + (size_t)prob * TSLAB;

    // persistent per-lane state
    float brow[8], browW[8], rightraw[8], rightW[8];
    float brold = BIGV, v00 = BIGV;
#pragma unroll
    for (int t = 0; t < 8; ++t) {
        brow[t] = BIGV; browW[t] = BIGV; rightraw[t] = BIGV; rightW[t] = BIGV;
    }

    f32x4 bufA[16], bufB[16];

    // coalesced load of this lane's tile on diagonal sp into buf
    auto load_diag = [&](int sp, f32x4* buf) {
        if (sp > 100) sp = 100;
        int len = diag_len(sp), i0 = diag_i0(sp), Cs = diag_Cs(sp);
        int pos = lane - i0;
        pos = pos < 0 ? 0 : pos;
        pos = pos > len - 1 ? len - 1 : pos;
        const float* srcb = Dp + Cs*64 + pos*4;
        int str = len * 4;
#pragma unroll
        for (int k = 0; k < 16; ++k)
            buf[k] = *(const f32x4*)(srcb + k*str);
    };

#define TILE_STEP(CUR, NXT, SVAL, DO_LOAD)                                    \
    {                                                                          \
        const int s_ = (SVAL);                                                 \
        if (DO_LOAD) {                                                         \
            load_diag(s_ + 1, NXT);                                            \
            __builtin_amdgcn_sched_barrier(0);  /* loads stay before compute */\
        }                                                                      \
        bool jz = (s_ == lane);            /* J == 0 */                        \
        float brnew = brow[7];                                                 \
        _Pragma("unroll")                                                      \
        for (int c = 0; c < 8; ++c) {                                          \
            brow[c] = wave_shr1(brow[c], BIGV);                                \
            browW[c] = brow[c] + WARP_PEN;                                     \
        }                                                                      \
        float corner = wave_shr1(brold, BIGV);                                 \
        if (jz) corner = (lane == 0) ? 0.f : BIGV;                             \
        float dprev = corner;                                                  \
        _Pragma("unroll")                                                      \
        for (int r = 0; r < 8; ++r) {                                          \
            float leftW = jz ? BIGV : rightW[r];                               \
            float dnextrow = jz ? BIGV : rightraw[r];                          \
            float diag = dprev;                                                \
            _Pragma("unroll")                                                  \
            for (int ch = 0; ch < 2; ++ch) {                                   \
                f32x4 dvv = CUR[r*2 + ch];                                     \
                _Pragma("unroll")                                              \
                for (int cc = 0; cc < 4; ++cc) {                               \
                    const int c = ch*4 + cc;                                   \
                    float v = fminf(fminf(diag, browW[c]), leftW) + dvv[cc];   \
                    if (r == 0 && c == 0) v00 = v;                             \
                    float t_ = brow[c];                                        \
                    brow[c] = v;                                               \
                    float vW = v + WARP_PEN;                                   \
                    browW[c] = vW;                                             \
                    leftW = vW;                                                \
                    diag = t_;                                                 \
                }                                                              \
            }                                                                  \
            rightraw[r] = brow[7];                                             \
            rightW[r]   = browW[7];                                            \
            dprev = dnextrow;                                                  \
        }                                                                      \
        brold = brnew;                                                         \
    }

    load_diag(0, bufA);

    for (int sb = 0; sb < 100; sb += 2) {
        TILE_STEP(bufA, bufB, sb,     1)
        TILE_STEP(bufB, bufA, sb + 1, 1)
    }
    TILE_STEP(bufA, bufB, 100, 0)   // final tile-diagonal
#undef TILE_STEP

    // R[400][400] = tile(50,50) cell (0,0), computed at s=100 by lane 50
    if (lane == 50) atomicAdd(&acc[6 + (prob >> 3)], v00);
}

// ---------------- kernel 5: assemble outputs ----------------
__global__ void finalize(const float* __restrict__ acc,
                         const float* __restrict__ dur,
                         const float* __restrict__ pit,
                         float* __restrict__ out) {
    if (threadIdx.x != 0 || blockIdx.x != 0) return;
    float t[6] = {0.f, 0.f, 0.f, 0.f, 0.f, 0.f};
    for (int s = 0; s < 8; ++s)
        for (int c = 0; c < 6; ++c)
            t[c] += acc[SLOT_OFF + s*16 + c];
    float gen  = t[0] / 3200.f;
    float e2e  = t[1] / 3200.f;
    float fm   = 4.f * t[2] / 409600.f;
    float melv = 45.f * t[3] / 256000.f;
    float d    = dur[0];
    float p    = pit[0];
    float kl   = acc[6] / t[4];
    float klf  = acc[7] / t[5];
    out[0] = gen; out[1] = e2e; out[2] = fm; out[3] = melv;
    out[4] = d;   out[5] = p;   out[6] = kl; out[7] = klf;
    out[8] = gen + e2e + fm + melv + d + p + kl + klf;
}

// ---------------- launch ----------------
extern "C" void kernel_launch(void* const* d_in, const int* in_sizes, int n_in,
                              void* d_out, int out_size, void* d_ws, size_t ws_size,
                              hipStream_t stream) {
    const float* mel    = (const float*)d_in[0];
    const float* melh   = (const float*)d_in[1];
    const float* sg     = (const float*)d_in[2];
    const float* se     = (const float*)d_in[3];
    const float* fr     = (const float*)d_in[4];
    const float* ff     = (const float*)d_in[5];
    const float* dur    = (const float*)d_in[6];
    const float* pit    = (const float*)d_in[7];
    const float* z_p    = (const float*)d_in[8];
    const float* m_p    = (const float*)d_in[9];
    const float* logs_p = (const float*)d_in[10];
    const float* z_q    = (const float*)d_in[11];
    const float* m_q    = (const float*)d_in[12];
    const float* logs_q = (const float*)d_in[13];
    const int*   p_mask = (const int*)d_in[14];
    const int*   z_mask = (const int*)d_in[15];
    float* ws  = (float*)d_ws;
    float* out = (float*)d_out;

    hipMemsetAsync(ws, 0, 160 * sizeof(float), stream);
    colsum<<<B*7, 256, 0, stream>>>(logs_p, m_p, logs_q, m_q, ws);
    fused_kl_scalar<<<KLBLOCKS + SBLOCKS, 256, 0, stream>>>(
        z_p, m_p, logs_p, z_q, m_q, logs_q, p_mask, z_mask, ws,
        mel, melh, sg, se, fr, ff);
    dtw_diag<<<NPROB, 64, 0, stream>>>(ws + DMAT_OFF, ws);
    finalize<<<1, 64, 0, stream>>>(ws, dur, pit, out);
}

// Round 20
// 140.598 us; speedup vs baseline: 1.1100x; 1.1100x over previous
//
#include <hip/hip_runtime.h>
#include <math.h>

// ---------------- constants ----------------
#define BIGV      1e9f
#define WARP_PEN  134.4f
#define MASK_INF_C 100000.0f

#define B   8
#define H   192
#define T   400
#define NP  401                  // padded matrix dim (0..400)
#define NPROB 16                 // 2 dirs x 8 batches
#define TSLAB 166464             // diag-staged D floats per problem (2601 tiles x 64)
#define SBLOCKS 768              // scalar-loss blocks in fused kernel
#define KLBLOCKS (49 * NPROB)    // 784 kl_gemm blocks

typedef float f32x4 __attribute__((ext_vector_type(4)));

// ---------------- workspace layout (float offsets) ----------------
#define SLOT_OFF 16
#define LSP_OFF 160
#define LSQ_OFF (160 + B*T)
#define C1P_OFF (160 + 2*B*T)
#define C1Q_OFF (160 + 3*B*T)
#define DMAT_OFF (160 + 4*B*T)   // 12960 floats, 16B aligned

// Diagonal-staged tile layout (verified R16/R17).
__device__ __forceinline__ int diag_len(int s) { return (s <= 50) ? s + 1 : 101 - s; }
__device__ __forceinline__ int diag_i0 (int s) { return (s <= 50) ? 0 : s - 50; }
__device__ __forceinline__ int diag_Cs (int s) {
    return (s <= 51) ? s * (s + 1) / 2 : 2601 - (101 - s) * (102 - s) / 2;
}

// DPP wave_shr:1 — lane i gets src from lane i-1; lane 0 gets `fill`.
__device__ __forceinline__ float wave_shr1(float src, float fill) {
    int r = __builtin_amdgcn_update_dpp(__float_as_int(fill), __float_as_int(src),
                                        0x138 /*wave_shr:1*/, 0xf, 0xf, false);
    return __int_as_float(r);
}

// ---------------- kernel 2: per-(b,t) column sums (4-way h-split) ----------
__global__ __launch_bounds__(256)
void colsum(const float* __restrict__ logs_p, const float* __restrict__ m_p,
            const float* __restrict__ logs_q, const float* __restrict__ m_q,
            float* __restrict__ ws) {
    int b = blockIdx.x / 7;
    int lane = threadIdx.x & 63;
    int hq = threadIdx.x >> 6;                 // 0..3, 48 h each
    int t = (blockIdx.x % 7) * 64 + lane;
    __shared__ float part[4][4][64];
    float lp_s = 0.f, lq_s = 0.f, c1p = 0.f, c1q = 0.f;
    if (t < T) {
        int base = b*H*T + hq*48*T + t;
        const float* LP = logs_p + base;
        const float* MP = m_p   + base;
        const float* LQ = logs_q + base;
        const float* MQ = m_q   + base;
#pragma unroll 4
        for (int h = 0; h < 48; ++h) {
            float lp = LP[h*T], mp = MP[h*T];
            float lq = LQ[h*T], mq = MQ[h*T];
            lp_s += lp;
            lq_s += lq;
            c1p += __expf(-2.f*lp) * mp * mp;
            c1q += __expf(-2.f*lq) * mq * mq;
        }
    }
    part[hq][0][lane] = lp_s;
    part[hq][1][lane] = lq_s;
    part[hq][2][lane] = c1p;
    part[hq][3][lane] = c1q;
    __syncthreads();
    if (hq == 0 && t < T) {
        float a0 = part[0][0][lane] + part[1][0][lane] + part[2][0][lane] + part[3][0][lane];
        float a1 = part[0][1][lane] + part[1][1][lane] + part[2][1][lane] + part[3][1][lane];
        float a2 = part[0][2][lane] + part[1][2][lane] + part[2][2][lane] + part[3][2][lane];
        float a3 = part[0][3][lane] + part[1][3][lane] + part[2][3][lane] + part[3][3][lane];
        ws[LSP_OFF + b*T + t] = a0;
        ws[LSQ_OFF + b*T + t] = a1;
        ws[C1P_OFF + b*T + t] = a2;
        ws[C1Q_OFF + b*T + t] = a3;
    }
}

// ---------------- fused kernel: KL GEMM (blocks 0..783) + scalar losses ----
// KH=32 (R18's proven config: 70us; R19's KH=16 regressed — grid supplies
// only ~6 blocks/CU so the occupancy cap wasn't binding, and 2x barriers
// dropped VALUBusy 33->27%).
#define TILE 64
#define KH 32
__global__ __launch_bounds__(256)
void fused_kl_scalar(const float* __restrict__ z_p, const float* __restrict__ m_p,
                     const float* __restrict__ logs_p,
                     const float* __restrict__ z_q, const float* __restrict__ m_q,
                     const float* __restrict__ logs_q,
                     const int* __restrict__ p_mask, const int* __restrict__ z_mask,
                     float* __restrict__ ws,
                     const float* __restrict__ mel, const float* __restrict__ melh,
                     const float* __restrict__ sg,  const float* __restrict__ se,
                     const float* __restrict__ fr,  const float* __restrict__ ff) {
    __shared__ __align__(16) float As [KH][TILE+4];
    __shared__ __align__(16) float AMs[KH][TILE+4];
    __shared__ __align__(16) float Zs [KH][TILE+4];
    __shared__ __align__(16) float Z2s[KH][TILE+4];
    __shared__ float red[4][8];

    if (blockIdx.x < KLBLOCKS) {
        // ---------------- kl_gemm path ----------------
        int prob = blockIdx.x / 49;
        int bx   = blockIdx.x % 49;
        int dir = prob >> 3, b = prob & 7;
        int tp = bx / 7, tq = bx % 7;
        int p0 = tp * TILE, q0 = tq * TILE;

        const float* lp_arr = dir ? logs_q : logs_p;
        const float* m_arr  = dir ? m_q    : m_p;
        const float* z_arr  = dir ? z_q    : z_p;
        const float* Lp = ws + (dir ? LSQ_OFF : LSP_OFF) + b*T;
        const float* Lq = ws + (dir ? LSP_OFF : LSQ_OFF) + b*T;
        const float* C1 = ws + (dir ? C1Q_OFF : C1P_OFF) + b*T;
        const int* rmask = dir ? z_mask : p_mask;
        const int* cmask = dir ? p_mask : z_mask;

        int tid = threadIdx.x;
        int tx = tid & 15, ty = tid >> 4;

        float acc1[4][4] = {{0.f}}, acc2[4][4] = {{0.f}};

        const float* lpB = lp_arr + b*H*T;
        const float* mB  = m_arr  + b*H*T;
        const float* zB  = z_arr  + b*H*T;

        for (int h0 = 0; h0 < H; h0 += KH) {
            for (int e = tid; e < KH*TILE; e += 256) {
                int hh = e >> 6, tt = e & 63;
                int pg = p0 + tt; if (pg > T-1) pg = T-1;
                int qg = q0 + tt; if (qg > T-1) qg = T-1;
                float lp = lpB[(h0+hh)*T + pg];
                float mv = mB [(h0+hh)*T + pg];
                float a  = __expf(-2.f*lp);
                As [hh][tt] = a;
                AMs[hh][tt] = a * mv;
                float zv = zB[(h0+hh)*T + qg];
                Zs [hh][tt] = zv;
                Z2s[hh][tt] = zv * zv;
            }
            __syncthreads();
#pragma unroll 8
            for (int hh = 0; hh < KH; ++hh) {
                const float4 av  = *(const float4*)(&As [hh][ty*4]);
                const float4 amv = *(const float4*)(&AMs[hh][ty*4]);
                const float4 zv  = *(const float4*)(&Zs [hh][tx*4]);
                const float4 z2v = *(const float4*)(&Z2s[hh][tx*4]);
                const float pa[4]  = {av.x, av.y, av.z, av.w};
                const float pam[4] = {amv.x, amv.y, amv.z, amv.w};
                const float qz[4]  = {zv.x, zv.y, zv.z, zv.w};
                const float qz2[4] = {z2v.x, z2v.y, z2v.z, z2v.w};
#pragma unroll
                for (int ii = 0; ii < 4; ++ii)
#pragma unroll
                    for (int jj = 0; jj < 4; ++jj) {
                        acc1[ii][jj] = fmaf(pa[ii],  qz2[jj], acc1[ii][jj]);
                        acc2[ii][jj] = fmaf(pam[ii], qz[jj],  acc2[ii][jj]);
                    }
            }
            __syncthreads();
        }

        // epilogue: kl value + pad/mask, DIAG-STAGED write (verified R16)
        float* Dm = ws + DMAT_OFF + (size_t)prob * TSLAB;
#pragma unroll
        for (int ii = 0; ii < 4; ++ii) {
            int p = p0 + ty*4 + ii;
            if (p > NP-1) continue;
            int pc = p < T ? p : T-1;
            float lpv = Lp[pc];
            float c1v = C1[pc];
            bool pmv = (p < T) && (rmask[b*T + p] != 0);
#pragma unroll
            for (int jj = 0; jj < 4; ++jj) {
                int q = q0 + tx*4 + jj;
                if (q > NP-1) continue;
                int qc = q < T ? q : T-1;
                bool qmv = (q < T) && (cmask[b*T + q] != 0);
                float val = lpv - Lq[qc] - 0.5f*(float)H
                          + 0.5f*(acc1[ii][jj] - 2.f*acc2[ii][jj] + c1v);
                float outv = (pmv != qmv) ? MASK_INF_C : ((!pmv && !qmv) ? 0.f : val);
                int I8 = p >> 3, J8 = q >> 3, sdg = I8 + J8;
                int len = diag_len(sdg), i0 = diag_i0(sdg), Cs = diag_Cs(sdg);
                int k = (p & 7) * 2 + ((q & 7) >> 2);
                int off = Cs*64 + (k*len + (I8 - i0))*4 + (q & 3);
                Dm[off] = outv;
            }
        }
    } else {
        // ---------------- scalar losses path ----------------
        float s0 = 0.f, s1 = 0.f, s2 = 0.f, s3 = 0.f, s4 = 0.f, s5 = 0.f;
        int tid = (blockIdx.x - KLBLOCKS) * 256 + threadIdx.x;
        const int stride = SBLOCKS * 256;

        const float4* fr4 = (const float4*)fr;
        const float4* ff4 = (const float4*)ff;
        for (int i = tid; i < 3072000; i += stride) {
            float4 a = fr4[i], b = ff4[i];
            s2 += fabsf(a.x - b.x) + fabsf(a.y - b.y) + fabsf(a.z - b.z) + fabsf(a.w - b.w);
        }
        const float4* m4 = (const float4*)mel;
        const float4* mh4 = (const float4*)melh;
        for (int i = tid; i < 64000; i += stride) {
            float4 a = m4[i], b = mh4[i];
            s3 += fabsf(a.x - b.x) + fabsf(a.y - b.y) + fabsf(a.z - b.z) + fabsf(a.w - b.w);
        }
        const float4* g4 = (const float4*)sg;
        const float4* e4 = (const float4*)se;
        for (int i = tid; i < 4800; i += stride) {
            float4 a = g4[i], b = e4[i];
            float gx = 1.f - a.x, gy = 1.f - a.y, gz = 1.f - a.z, gw = 1.f - a.w;
            s0 += gx*gx + gy*gy + gz*gz + gw*gw;
            float hx = 1.f - b.x, hy = 1.f - b.y, hz = 1.f - b.z, hw = 1.f - b.w;
            s1 += hx*hx + hy*hy + hz*hz + hw*hw;
        }
        for (int i = tid; i < B*T; i += stride) {
            s4 += (float)p_mask[i];
            s5 += (float)z_mask[i];
        }
        for (int off = 32; off > 0; off >>= 1) {
            s0 += __shfl_down(s0, off); s1 += __shfl_down(s1, off);
            s2 += __shfl_down(s2, off); s3 += __shfl_down(s3, off);
            s4 += __shfl_down(s4, off); s5 += __shfl_down(s5, off);
        }
        int wid = threadIdx.x >> 6;
        if ((threadIdx.x & 63) == 0) {
            red[wid][0] = s0; red[wid][1] = s1; red[wid][2] = s2;
            red[wid][3] = s3; red[wid][4] = s4; red[wid][5] = s5;
        }
        __syncthreads();
        if (threadIdx.x == 0) {
            float t0 = 0.f, t1 = 0.f, t2 = 0.f, t3 = 0.f, t4 = 0.f, t5 = 0.f;
#pragma unroll
            for (int w = 0; w < 4; ++w) {
                t0 += red[w][0]; t1 += red[w][1]; t2 += red[w][2];
                t3 += red[w][3]; t4 += red[w][4]; t5 += red[w][5];
            }
            float* slot = ws + SLOT_OFF + (blockIdx.x & 7) * 16;
            atomicAdd(&slot[0], t0); atomicAdd(&slot[1], t1);
            atomicAdd(&slot[2], t2); atomicAdd(&slot[3], t3);
            atomicAdd(&slot[4], t4); atomicAdd(&slot[5], t5);
        }
    }
}

// ---------------- kernel 4: DTW tile wavefront — STANDALONE ----------------
// 16 blocks x 64 threads, launch_bounds(64,1) -> RA budget 512 VGPR.
// TRIPLE-buffered register staging: loads for diag s+2 issue at step s,
// giving 2 full tile-computes (~1000-1300cy) of load-to-use distance —
// exceeds HBM-miss latency even with conservative compiler waitcnts.
// Static 3-phase rotation (no runtime indexing — rule #20).
__global__ __launch_bounds__(64, 1)
void dtw_diag(const float* __restrict__ Dd, float* __restrict__ acc) {
    int prob = blockIdx.x;
    int lane = threadIdx.x;
    const float* Dp = Dd + (size_t)prob * TSLAB;

    // persistent per-lane state
    float brow[8], browW[8], rightraw[8], rightW[8];
    float brold = BIGV, v00 = BIGV;
#pragma unroll
    for (int t = 0; t < 8; ++t) {
        brow[t] = BIGV; browW[t] = BIGV; rightraw[t] = BIGV; rightW[t] = BIGV;
    }

    f32x4 bufA[16], bufB[16], bufC[16];

    // coalesced load of this lane's tile on diagonal sp into buf
    auto load_diag = [&](int sp, f32x4* buf) {
        if (sp > 100) sp = 100;
        int len = diag_len(sp), i0 = diag_i0(sp), Cs = diag_Cs(sp);
        int pos = lane - i0;
        pos = pos < 0 ? 0 : pos;
        pos = pos > len - 1 ? len - 1 : pos;
        const float* srcb = Dp + Cs*64 + pos*4;
        int str = len * 4;
#pragma unroll
        for (int k = 0; k < 16; ++k)
            buf[k] = *(const f32x4*)(srcb + k*str);
    };

#define TILE_STEP(CUR, NXT, SVAL, DO_LOAD)                                    \
    {                                                                          \
        const int s_ = (SVAL);                                                 \
        if (DO_LOAD) {                                                         \
            load_diag(s_ + 2, NXT);                                            \
            __builtin_amdgcn_sched_barrier(0);  /* loads stay before compute */\
        }                                                                      \
        bool jz = (s_ == lane);            /* J == 0 */                        \
        float brnew = brow[7];                                                 \
        _Pragma("unroll")                                                      \
        for (int c = 0; c < 8; ++c) {                                          \
            brow[c] = wave_shr1(brow[c], BIGV);                                \
            browW[c] = brow[c] + WARP_PEN;                                     \
        }                                                                      \
        float corner = wave_shr1(brold, BIGV);                                 \
        if (jz) corner = (lane == 0) ? 0.f : BIGV;                             \
        float dprev = corner;                                                  \
        _Pragma("unroll")                                                      \
        for (int r = 0; r < 8; ++r) {                                          \
            float leftW = jz ? BIGV : rightW[r];                               \
            float dnextrow = jz ? BIGV : rightraw[r];                          \
            float diag = dprev;                                                \
            _Pragma("unroll")                                                  \
            for (int ch = 0; ch < 2; ++ch) {                                   \
                f32x4 dvv = CUR[r*2 + ch];                                     \
                _Pragma("unroll")                                              \
                for (int cc = 0; cc < 4; ++cc) {                               \
                    const int c = ch*4 + cc;                                   \
                    float v = fminf(fminf(diag, browW[c]), leftW) + dvv[cc];   \
                    if (r == 0 && c == 0) v00 = v;                             \
                    float t_ = brow[c];                                        \
                    brow[c] = v;                                               \
                    float vW = v + WARP_PEN;                                   \
                    browW[c] = vW;                                             \
                    leftW = vW;                                                \
                    diag = t_;                                                 \
                }                                                              \
            }                                                                  \
            rightraw[r] = brow[7];                                             \
            rightW[r]   = browW[7];                                            \
            dprev = dnextrow;                                                  \
        }                                                                      \
        brold = brnew;                                                         \
    }

    // prologue: diag 0 -> A, diag 1 -> B
    load_diag(0, bufA);
    load_diag(1, bufB);

    // steady state: compute buf[s%3], load s+2 -> buf[(s+2)%3]
    for (int sb = 0; sb < 99; sb += 3) {
        TILE_STEP(bufA, bufC, sb,     1)
        TILE_STEP(bufB, bufA, sb + 1, 1)
        TILE_STEP(bufC, bufB, sb + 2, 1)
    }
    TILE_STEP(bufA, bufC, 99,  0)   // diag 99 (loaded at s=97 into A)
    TILE_STEP(bufB, bufC, 100, 0)   // diag 100 (loaded at s=98 into B)
#undef TILE_STEP

    // R[400][400] = tile(50,50) cell (0,0), computed at s=100 by lane 50
    if (lane == 50) atomicAdd(&acc[6 + (prob >> 3)], v00);
}

// ---------------- kernel 5: assemble outputs ----------------
__global__ void finalize(const float* __restrict__ acc,
                         const float* __restrict__ dur,
                         const float* __restrict__ pit,
                         float* __restrict__ out) {
    if (threadIdx.x != 0 || blockIdx.x != 0) return;
    float t[6] = {0.f, 0.f, 0.f, 0.f, 0.f, 0.f};
    for (int s = 0; s < 8; ++s)
        for (int c = 0; c < 6; ++c)
            t[c] += acc[SLOT_OFF + s*16 + c];
    float gen  = t[0] / 3200.f;
    float e2e  = t[1] / 3200.f;
    float fm   = 4.f * t[2] / 409600.f;
    float melv = 45.f * t[3] / 256000.f;
    float d    = dur[0];
    float p    = pit[0];
    float kl   = acc[6] / t[4];
    float klf  = acc[7] / t[5];
    out[0] = gen; out[1] = e2e; out[2] = fm; out[3] = melv;
    out[4] = d;   out[5] = p;   out[6] = kl; out[7] = klf;
    out[8] = gen + e2e + fm + melv + d + p + kl + klf;
}

// ---------------- launch ----------------
extern "C" void kernel_launch(void* const* d_in, const int* in_sizes, int n_in,
                              void* d_out, int out_size, void* d_ws, size_t ws_size,
                              hipStream_t stream) {
    const float* mel    = (const float*)d_in[0];
    const float* melh   = (const float*)d_in[1];
    const float* sg     = (const float*)d_in[2];
    const float* se     = (const float*)d_in[3];
    const float* fr     = (const float*)d_in[4];
    const float* ff     = (const float*)d_in[5];
    const float* dur    = (const float*)d_in[6];
    const float* pit    = (const float*)d_in[7];
    const float* z_p    = (const float*)d_in[8];
    const float* m_p    = (const float*)d_in[9];
    const float* logs_p = (const float*)d_in[10];
    const float* z_q    = (const float*)d_in[11];
    const float* m_q    = (const float*)d_in[12];
    const float* logs_q = (const float*)d_in[13];
    const int*   p_mask = (const int*)d_in[14];
    const int*   z_mask = (const int*)d_in[15];
    float* ws  = (float*)d_ws;
    float* out = (float*)d_out;

    hipMemsetAsync(ws, 0, 160 * sizeof(float), stream);
    colsum<<<B*7, 256, 0, stream>>>(logs_p, m_p, logs_q, m_q, ws);
    fused_kl_scalar<<<KLBLOCKS + SBLOCKS, 256, 0, stream>>>(
        z_p, m_p, logs_p, z_q, m_q, logs_q, p_mask, z_mask, ws,
        mel, melh, sg, se, fr, ff);
    dtw_diag<<<NPROB, 64, 0, stream>>>(ws + DMAT_OFF, ws);
    finalize<<<1, 64, 0, stream>>>(ws, dur, pit, out);
}